// Round 5
// baseline (286.727 us; speedup 1.0000x reference)
//
#include <hip/hip_runtime.h>
#include <hip/hip_fp16.h>
#include <cmath>

// Problem dims: B=4, C=64, H=W=256, k=3
namespace {
constexpr int Bn = 4, Cn = 64, Hn = 256, Wn = 256;
constexpr int HWn = Hn * Wn;              // 65536
// ws layout, BYTE offsets:
constexpr size_t OFF_PRE_LOW  = 0;          // a_low pre, NHWC f16, 33554432 B
constexpr size_t OFF_PRE_HIGH = 33554432;   // a_high pre, NHWC f16
constexpr size_t OFF_OM_COL   = 67108864;   // om col (B,9,H,W) f32, 9437184 B
constexpr size_t OFF_OM_ROW   = 76546048;   // om row f32
constexpr size_t OFF_W1       = 85983232;   // [c][j] 64*32 u32 (half2-dup)
constexpr size_t OFF_W2       = 85991424;   // [j][o] 32*64 u32 (half2-dup)
constexpr size_t OFF_WOF16    = 85999616;   // offset-conv weights, half2-dup u32, [c][k][18]
constexpr size_t OFF_WPACK    = 86013440;   // MFMA A-frag packed f16, 2 modes * 12288 halves
// total ~86 MB
}

typedef _Float16 f16x8 __attribute__((ext_vector_type(8)));
typedef float f32x4 __attribute__((ext_vector_type(4)));

__device__ __forceinline__ float sigm(float x) { return 1.f / (1.f + __expf(-x)); }
__device__ __forceinline__ __half2 bc2(unsigned u) { return __builtin_bit_cast(__half2, u); }
__device__ __forceinline__ unsigned u32of(__half2 h) { return __builtin_bit_cast(unsigned, h); }

// ---------------- weight repack (tiny) ----------------
__global__ void k_repack(const float* __restrict__ pw1, const float* __restrict__ pw2,
                         const float* __restrict__ owc, const float* __restrict__ owr,
                         const float* __restrict__ wc,  const float* __restrict__ wr,
                         char* __restrict__ ws8)
{
    unsigned* W1h = (unsigned*)(ws8 + OFF_W1);
    unsigned* W2h = (unsigned*)(ws8 + OFF_W2);
    unsigned* Wo2 = (unsigned*)(ws8 + OFF_WOF16);
    __half*   Wp  = (__half*)(ws8 + OFF_WPACK);
    int t = blockIdx.x * 256 + threadIdx.x;
    int stride = gridDim.x * 256;
    for (int i = t; i < 2048; i += stride) {
        int c = i >> 5, j = i & 31;
        W1h[i] = u32of(__float2half2_rn(pw1[j * 64 + c]));
    }
    for (int i = t; i < 2048; i += stride) {
        int j = i >> 6, o = i & 63;
        W2h[i] = u32of(__float2half2_rn(pw2[o * 32 + j]));
    }
    // offset-conv weights as duplicated half2: layout [c][k][18]
    for (int i = t; i < 3456; i += stride) {
        int ck = i / 18, d = i - ck * 18;
        float v = (d < 9) ? owc[d * 192 + ck] : owr[(d - 9) * 192 + ck];
        Wo2[i] = u32of(__float2half2_rn(v));
    }
    // MFMA A-fragment pack (f16): k' = tap*64 + c; per mode:
    // Wp[((s*4+wv)*64 + lane)*8 + e] = w[o=wv*16+(lane&15)][k'=32s+(lane>>4)*8+e]
    for (int i = t; i < 24576; i += stride) {
        int m = i >= 12288;
        int rem = i - m * 12288;
        int e = rem & 7, l = (rem >> 3) & 63, wv = (rem >> 9) & 3, s = rem >> 11;
        int kk = 32 * s + (l >> 4) * 8 + e;
        int o = wv * 16 + (l & 15);
        int c = kk & 63, tap = kk >> 6;
        const float* src = m ? wr : wc;
        Wp[i] = __float2half(src[o * 192 + c * 3 + tap]);
    }
}

// ---------------- preprocess: 1x1 conv 64->32->64, 2 pixels/thread via hfma2 ----------------
// NCHW f32 in -> NHWC f16 (ws) + NCHW f16 copy of a_low (d_out scratch)
__global__ __launch_bounds__(256) void k_pre(const float* __restrict__ alow,
                                             const float* __restrict__ ahigh,
                                             const float* __restrict__ b1,
                                             const float* __restrict__ b2,
                                             char* __restrict__ ws8,
                                             __half* __restrict__ anchw)
{
    const unsigned* __restrict__ W1h = (const unsigned*)(ws8 + OFF_W1);
    const unsigned* __restrict__ W2h = (const unsigned*)(ws8 + OFF_W2);
    int t = blockIdx.x * 256 + threadIdx.x;      // [0, 262144)
    int tensor = t >> 17;
    int pr = t & 131071;                          // pixel-pair index
    int pix0 = pr * 2;
    int b = pix0 >> 16;
    int hw = pix0 & 65535;
    const float* __restrict__ x = (tensor ? ahigh : alow) + (size_t)b * Cn * HWn + hw;

    __half2 hreg[32];
#pragma unroll
    for (int j = 0; j < 32; j++) hreg[j] = __float2half2_rn(b1[j]);
#pragma unroll 4
    for (int c = 0; c < 64; c++) {
        float2 xv = *reinterpret_cast<const float2*>(x + (size_t)c * HWn);
        __half2 xh = __float22half2_rn({xv.x, xv.y});
        const unsigned* wrow = W1h + c * 32;
#pragma unroll
        for (int j = 0; j < 32; j++) hreg[j] = __hfma2(bc2(wrow[j]), xh, hreg[j]);
    }
    __half2 acc[64];
#pragma unroll
    for (int o = 0; o < 64; o++) acc[o] = __float2half2_rn(b2[o]);
#pragma unroll
    for (int j = 0; j < 32; j++) {
        __half2 hv = hreg[j];
        const unsigned* wrow = W2h + j * 64;
#pragma unroll
        for (int o = 0; o < 64; o++) acc[o] = __hfma2(bc2(wrow[o]), hv, acc[o]);
    }
    // NHWC stores: pixel0 = lo halves, pixel1 = hi halves
    __half* __restrict__ outp = (__half*)(ws8 + (tensor ? OFF_PRE_HIGH : OFF_PRE_LOW)) + (size_t)pix0 * 64;
#pragma unroll
    for (int o = 0; o < 64; o += 8) {
        uint4 u0, u1;
        u0.x = u32of(__halves2half2(__low2half(acc[o + 0]), __low2half(acc[o + 1])));
        u0.y = u32of(__halves2half2(__low2half(acc[o + 2]), __low2half(acc[o + 3])));
        u0.z = u32of(__halves2half2(__low2half(acc[o + 4]), __low2half(acc[o + 5])));
        u0.w = u32of(__halves2half2(__low2half(acc[o + 6]), __low2half(acc[o + 7])));
        u1.x = u32of(__halves2half2(__high2half(acc[o + 0]), __high2half(acc[o + 1])));
        u1.y = u32of(__halves2half2(__high2half(acc[o + 2]), __high2half(acc[o + 3])));
        u1.z = u32of(__halves2half2(__high2half(acc[o + 4]), __high2half(acc[o + 5])));
        u1.w = u32of(__halves2half2(__high2half(acc[o + 6]), __high2half(acc[o + 7])));
        *reinterpret_cast<uint4*>(outp + o) = u0;
        *reinterpret_cast<uint4*>(outp + 64 + o) = u1;
    }
    if (tensor == 0) {
        // NCHW copy: half2 = 2 consecutive pixels -> coalesced u32 stores
        unsigned* __restrict__ np = (unsigned*)(anchw + (size_t)b * Cn * HWn) + (hw >> 1);
#pragma unroll
        for (int o = 0; o < 64; o++) np[o * (HWn / 2)] = u32of(acc[o]);
    }
}

// ---------------- offset convs: packed-f16, vectorized loads ----------------
__global__ __launch_bounds__(256) void k_om2(const __half* __restrict__ Anc,
                                             const float* __restrict__ ocb,
                                             const float* __restrict__ orb,
                                             char* __restrict__ ws8)
{
    const unsigned* __restrict__ Wo2 = (const unsigned*)(ws8 + OFF_WOF16);
    float* __restrict__ omc = (float*)(ws8 + OFF_OM_COL);
    float* __restrict__ omr = (float*)(ws8 + OFF_OM_ROW);
    int t = blockIdx.x * 256 + threadIdx.x;     // [0, B*H*W/4)
    int q = t & 63;
    int h = (t >> 6) & 255;
    int b = t >> 14;
    int w0 = q * 4;
    const __half* __restrict__ base = Anc + ((size_t)b * Cn) * HWn + (size_t)h * Wn + w0;

    const bool topOK = (h > 0), botOK = (h < Hn - 1);
    const bool lOK = (w0 > 0), rOK = (w0 + 4 < Wn);
    const int offT = topOK ? -Wn : 0;
    const int offB = botOK ? Wn : 0;
    const int offL = lOK ? -1 : 0;
    const int offR = rOK ? 4 : 3;

    const __half2 z = __float2half2_rn(0.f);
    const __half hz = __float2half(0.f);
    __half2 aC[9][2], aR[9][2];
#pragma unroll
    for (int d = 0; d < 9; d++) { aC[d][0] = z; aC[d][1] = z; aR[d][0] = z; aR[d][1] = z; }

    for (int c = 0; c < 64; c++) {
        const __half* pc = base + (size_t)c * HWn;
        uint2 qm = *reinterpret_cast<const uint2*>(pc + offT);
        uint2 q0 = *reinterpret_cast<const uint2*>(pc);
        uint2 qp = *reinterpret_cast<const uint2*>(pc + offB);
        __half L = lOK ? pc[offL] : hz;
        __half R = rOK ? pc[offR] : hz;
        __half2 m0 = topOK ? bc2(qm.x) : z, m1 = topOK ? bc2(qm.y) : z;
        __half2 c0 = bc2(q0.x), c1 = bc2(q0.y);
        __half2 p0 = botOK ? bc2(qp.x) : z, p1 = botOK ? bc2(qp.y) : z;
        __half2 X = __halves2half2(L, __low2half(c0));
        __half2 Y = __halves2half2(__high2half(c0), __low2half(c1));
        __half2 Z = __halves2half2(__high2half(c1), R);
        const unsigned* wb = Wo2 + c * 54;     // [k][18]
#pragma unroll
        for (int d = 0; d < 9; d++) {
            __half2 u0 = bc2(wb[d]), u1 = bc2(wb[18 + d]), u2 = bc2(wb[36 + d]);
            aC[d][0] = __hfma2(u0, m0, __hfma2(u1, c0, __hfma2(u2, p0, aC[d][0])));
            aC[d][1] = __hfma2(u0, m1, __hfma2(u1, c1, __hfma2(u2, p1, aC[d][1])));
            __half2 v0 = bc2(wb[9 + d]), v1 = bc2(wb[27 + d]), v2 = bc2(wb[45 + d]);
            aR[d][0] = __hfma2(v0, X, __hfma2(v1, c0, __hfma2(v2, Y, aR[d][0])));
            aR[d][1] = __hfma2(v0, Y, __hfma2(v1, c1, __hfma2(v2, Z, aR[d][1])));
        }
    }

    size_t ob = ((size_t)b * 9) * HWn + (size_t)h * Wn + w0;
#pragma unroll
    for (int d = 0; d < 9; d++) {
        float bcd = ocb[d], brd = orb[d];
        float4 vc = { __low2float(aC[d][0]) + bcd, __high2float(aC[d][0]) + bcd,
                      __low2float(aC[d][1]) + bcd, __high2float(aC[d][1]) + bcd };
        float4 vr = { __low2float(aR[d][0]) + brd, __high2float(aR[d][0]) + brd,
                      __low2float(aR[d][1]) + brd, __high2float(aR[d][1]) + brd };
        *reinterpret_cast<float4*>(omc + ob + (size_t)d * HWn) = vc;
        *reinterpret_cast<float4*>(omr + ob + (size_t)d * HWn) = vr;
    }
}

// ---------------- fused deformable conv (both dirs) + MFMA + epilogue ----------------
// 512 threads, 64 pixels/block. Gather: threads 0..383 own (mode,tap,pixel) with
// double-buffered corner loads (16 x 16B in flight). VB XOR-swizzled (slot^g&7).
// One barrier. 8 waves: waves 0-3 mode0 GEMM, 4-7 mode1. sigma via LDS (stride 66).
__global__ __launch_bounds__(512, 2) void k_dfuse(const float* __restrict__ bc,
                                                  const float* __restrict__ br,
                                                  float* __restrict__ out,
                                                  char* __restrict__ ws8)
{
    __shared__ __align__(16) unsigned smem[12288];   // 48 KB: VB u32[2][24][256]; EX f32[2][64][66] overlay

    const __half* __restrict__ A16  = (const __half*)(ws8 + OFF_PRE_LOW);
    const __half* __restrict__ Ah16 = (const __half*)(ws8 + OFF_PRE_HIGH);

    int blk = blockIdx.x;                 // ((b*H + h)*4 + wt)
    int wt = blk & 3, bh = blk >> 2, h = bh & 255, b = bh >> 8;
    int w0 = wt * 64;
    int tid = threadIdx.x;

    // ---- decode + gather (threads 0..383; waves 0-2 mode0, 3-5 mode1) ----
    if (tid < 384) {
        int m = tid >= 192 ? 1 : 0;
        int r = tid - m * 192;
        int tap = r >> 6, p = r & 63;
        int w = w0 + p;
        const float* __restrict__ om = (const float*)(ws8 + (m ? OFF_OM_ROW : OFF_OM_COL));
        size_t ob = ((size_t)b * 9 * Hn + h) * Wn + w;
        float dy = om[ob + (size_t)tap * HWn];
        float dx = om[ob + (size_t)(3 + tap) * HWn];
        float mm = om[ob + (size_t)(6 + tap) * HWn];
        float mask = sigm(mm);
        float py = dy + (float)h + (m ? 0.f : (float)(tap - 1));
        float px = dx + (float)w + (m ? (float)(tap - 1) : 0.f);
        float fy = floorf(py), fx = floorf(px);
        float ty = py - fy, tx = px - fx;
        int y0 = (int)fy, x0 = (int)fx;
        int y1 = y0 + 1, x1 = x0 + 1;
        float vy0 = ((unsigned)y0 < (unsigned)Hn) ? 1.f : 0.f;
        float vy1 = ((unsigned)y1 < (unsigned)Hn) ? 1.f : 0.f;
        float vx0 = ((unsigned)x0 < (unsigned)Wn) ? 1.f : 0.f;
        float vx1 = ((unsigned)x1 < (unsigned)Wn) ? 1.f : 0.f;
        int y0c = min(max(y0, 0), Hn - 1), y1c = min(max(y1, 0), Hn - 1);
        int x0c = min(max(x0, 0), Wn - 1), x1c = min(max(x1, 0), Wn - 1);
        float ry = 1.f - ty, rx = 1.f - tx;
        int pbase = b * HWn;
        __half2 wh[4];
        wh[0] = __float2half2_rn(ry * rx * mask * vy0 * vx0);
        wh[1] = __float2half2_rn(ry * tx * mask * vy0 * vx1);
        wh[2] = __float2half2_rn(ty * rx * mask * vy1 * vx0);
        wh[3] = __float2half2_rn(ty * tx * mask * vy1 * vx1);
        int cb[4];
        cb[0] = (pbase + y0c * Wn + x0c) * 8;     // uint4-index: pix*128B/16
        cb[1] = (pbase + y0c * Wn + x1c) * 8;
        cb[2] = (pbase + y1c * Wn + x0c) * 8;
        cb[3] = (pbase + y1c * Wn + x1c) * 8;
        const uint4* __restrict__ Au = (const uint4*)A16;
        const __half2 z = __float2half2_rn(0.f);

        uint4 ra[4], rb[4], na[4], nb[4];
#pragma unroll
        for (int i = 0; i < 4; i++) { ra[i] = Au[cb[i]]; rb[i] = Au[cb[i] + 1]; }
#pragma unroll
        for (int c4 = 0; c4 < 4; c4++) {
            if (c4 < 3) {
#pragma unroll
                for (int i = 0; i < 4; i++) {
                    na[i] = Au[cb[i] + (c4 + 1) * 2];
                    nb[i] = Au[cb[i] + (c4 + 1) * 2 + 1];
                }
            }
            __half2 hs[8];
#pragma unroll
            for (int j = 0; j < 8; j++) hs[j] = z;
#pragma unroll
            for (int i = 0; i < 4; i++) {
                hs[0] = __hfma2(bc2(ra[i].x), wh[i], hs[0]);
                hs[1] = __hfma2(bc2(ra[i].y), wh[i], hs[1]);
                hs[2] = __hfma2(bc2(ra[i].z), wh[i], hs[2]);
                hs[3] = __hfma2(bc2(ra[i].w), wh[i], hs[3]);
                hs[4] = __hfma2(bc2(rb[i].x), wh[i], hs[4]);
                hs[5] = __hfma2(bc2(rb[i].y), wh[i], hs[5]);
                hs[6] = __hfma2(bc2(rb[i].z), wh[i], hs[6]);
                hs[7] = __hfma2(bc2(rb[i].w), wh[i], hs[7]);
            }
            int g0 = tap * 8 + c4 * 2;
            uint4 lo = { u32of(hs[0]), u32of(hs[1]), u32of(hs[2]), u32of(hs[3]) };
            uint4 hi = { u32of(hs[4]), u32of(hs[5]), u32of(hs[6]), u32of(hs[7]) };
            int sl0 = p ^ (g0 & 7);
            int sl1 = p ^ ((g0 + 1) & 7);
            *reinterpret_cast<uint4*>(&smem[m * 6144 + (g0 + 0) * 256 + sl0 * 4]) = lo;
            *reinterpret_cast<uint4*>(&smem[m * 6144 + (g0 + 1) * 256 + sl1 * 4]) = hi;
            if (c4 < 3) {
#pragma unroll
                for (int i = 0; i < 4; i++) { ra[i] = na[i]; rb[i] = nb[i]; }
            }
        }
    }
    __syncthreads();

    // ---- GEMM: wave wv: mode = wv>>2, o-slice = (wv&3)*16 ----
    int wv = tid >> 6;
    int lane = tid & 63;
    int m = wv >> 2;
    int wq = wv & 3;
    int kb = lane >> 4, n = lane & 15;
    const f16x8* __restrict__ Wp = reinterpret_cast<const f16x8*>(ws8 + OFF_WPACK + (size_t)m * 24576);
    f32x4 zero = {0.f, 0.f, 0.f, 0.f};
    f32x4 acc[4] = {zero, zero, zero, zero};
#pragma unroll
    for (int s = 0; s < 6; s++) {
        f16x8 af = Wp[(s * 4 + wq) * 64 + lane];
        int rr = s * 4 + kb;
#pragma unroll
        for (int pt = 0; pt < 4; pt++) {
            int sl = (pt * 16 + n) ^ (rr & 7);
            f16x8 bf = *reinterpret_cast<const f16x8*>(&smem[m * 6144 + rr * 256 + sl * 4]);
            acc[pt] = __builtin_amdgcn_mfma_f32_16x16x32_f16(af, bf, acc[pt], 0, 0, 0);
        }
    }
    // sigma in regs
    const float* __restrict__ bias = m ? br : bc;
    float bv[4];
#pragma unroll
    for (int rg = 0; rg < 4; rg++) bv[rg] = bias[wq * 16 + kb * 4 + rg];
    float sg[4][4];
#pragma unroll
    for (int pt = 0; pt < 4; pt++)
#pragma unroll
        for (int rg = 0; rg < 4; rg++) sg[pt][rg] = sigm(acc[pt][rg] + bv[rg]);
    __syncthreads();
    // EX overlay: [m][o][66] f32
    float* EX = reinterpret_cast<float*>(smem);
#pragma unroll
    for (int pt = 0; pt < 4; pt++)
#pragma unroll
        for (int rg = 0; rg < 4; rg++)
            EX[m * 4224 + (wq * 16 + kb * 4 + rg) * 66 + (pt * 16 + n)] = sg[pt][rg];
    __syncthreads();

    // ---- epilogue: thread t: pixel p = t&63, o-group = t>>6 (8 o's) ----
    int p = tid & 63, og = tid >> 6;
    int o0 = og * 8;
    size_t pix = ((size_t)b * Hn + h) * Wn + (w0 + p);
    uint4 ua = *reinterpret_cast<const uint4*>(A16 + pix * 64 + o0);
    uint4 uh = *reinterpret_cast<const uint4*>(Ah16 + pix * 64 + o0);
    const __half* ap = reinterpret_cast<const __half*>(&ua);
    const __half* hp = reinterpret_cast<const __half*>(&uh);
    size_t outb = ((size_t)b * 64 + o0) * HWn + (size_t)h * Wn + w0 + p;
#pragma unroll
    for (int j = 0; j < 8; j++) {
        float sc = EX[(o0 + j) * 66 + p];
        float sr = EX[4224 + (o0 + j) * 66 + p];
        float av = __half2float(ap[j]);
        float hv = __half2float(hp[j]);
        out[outb + (size_t)j * HWn] = 2.f * av + (sc + sr) * hv;
    }
}

extern "C" void kernel_launch(void* const* d_in, const int* in_sizes, int n_in,
                              void* d_out, int out_size, void* d_ws, size_t ws_size,
                              hipStream_t stream)
{
    const float* a_low  = (const float*)d_in[0];
    const float* a_high = (const float*)d_in[1];
    const float* pre_w1 = (const float*)d_in[2];
    const float* pre_b1 = (const float*)d_in[3];
    const float* pre_w2 = (const float*)d_in[4];
    const float* pre_b2 = (const float*)d_in[5];
    const float* offc_w = (const float*)d_in[6];
    const float* offc_b = (const float*)d_in[7];
    const float* wc     = (const float*)d_in[8];
    const float* bc     = (const float*)d_in[9];
    const float* offr_w = (const float*)d_in[10];
    const float* offr_b = (const float*)d_in[11];
    const float* wr     = (const float*)d_in[12];
    const float* br     = (const float*)d_in[13];
    float* out = (float*)d_out;
    char* ws8  = (char*)d_ws;

    hipLaunchKernelGGL(k_repack, dim3(128), dim3(256), 0, stream,
                       pre_w1, pre_w2, offc_w, offr_w, wc, wr, ws8);
    // k_pre also writes NCHW f16 copy of preprocessed a_low into d_out
    // (scratch; fully overwritten by k_dfuse epilogue)
    hipLaunchKernelGGL(k_pre, dim3(1024), dim3(256), 0, stream,
                       a_low, a_high, pre_b1, pre_b2, ws8, (__half*)d_out);
    hipLaunchKernelGGL(k_om2, dim3(256), dim3(256), 0, stream,
                       (const __half*)d_out, offc_b, offr_b, ws8);
    hipLaunchKernelGGL(k_dfuse, dim3(4096), dim3(512), 0, stream,
                       bc, br, out, ws8);
}

// Round 6
// 247.824 us; speedup vs baseline: 1.1570x; 1.1570x over previous
//
#include <hip/hip_runtime.h>
#include <hip/hip_fp16.h>
#include <cmath>

// Problem dims: B=4, C=64, H=W=256, k=3
namespace {
constexpr int Bn = 4, Cn = 64, Hn = 256, Wn = 256;
constexpr int HWn = Hn * Wn;              // 65536
// ws layout, BYTE offsets:
constexpr size_t OFF_PRE_LOW  = 0;          // a_low pre, NHWC f16, 33554432 B
constexpr size_t OFF_PRE_HIGH = 33554432;   // a_high pre, NCHW f16 (epilogue-only reader)
constexpr size_t OFF_OM_COL   = 67108864;   // om col (B,9,H,W) f32, 9437184 B
constexpr size_t OFF_OM_ROW   = 76546048;   // om row f32
constexpr size_t OFF_W1       = 85983232;   // [c][jp] 64*16 u32 (mid-channel-paired half2)
constexpr size_t OFF_W2       = 85991424;   // [j][op] 32*32 u32 (out-channel-paired half2)
constexpr size_t OFF_WOF16    = 85999616;   // offset-conv weights, half2-dup u32, [c][k][18]
constexpr size_t OFF_WPACK    = 86013440;   // MFMA A-frag packed f16, 2 modes * 12288 halves
// total ~86 MB. NCHW f16 copy of preprocessed a_low lives in d_out
// (scratch; fully overwritten by k_dfuse epilogue, which does not read it).
}

typedef _Float16 f16x8 __attribute__((ext_vector_type(8)));
typedef float f32x4 __attribute__((ext_vector_type(4)));

__device__ __forceinline__ float sigm(float x) { return 1.f / (1.f + __expf(-x)); }
__device__ __forceinline__ __half2 bc2(unsigned u) { return __builtin_bit_cast(__half2, u); }
__device__ __forceinline__ unsigned u32of(__half2 h) { return __builtin_bit_cast(unsigned, h); }

// ---------------- weight repack (tiny) ----------------
__global__ void k_repack(const float* __restrict__ pw1, const float* __restrict__ pw2,
                         const float* __restrict__ owc, const float* __restrict__ owr,
                         const float* __restrict__ wc,  const float* __restrict__ wr,
                         char* __restrict__ ws8)
{
    unsigned* W1p = (unsigned*)(ws8 + OFF_W1);
    unsigned* W2p = (unsigned*)(ws8 + OFF_W2);
    unsigned* Wo2 = (unsigned*)(ws8 + OFF_WOF16);
    __half*   Wp  = (__half*)(ws8 + OFF_WPACK);
    int t = blockIdx.x * 256 + threadIdx.x;
    int stride = gridDim.x * 256;
    // W1 paired over mid-channel j: W1p[c][jp] = (w1[2jp][c], w1[2jp+1][c])
    for (int i = t; i < 1024; i += stride) {
        int c = i >> 4, jp = i & 15;
        W1p[i] = u32of(__float22half2_rn({pw1[(2 * jp) * 64 + c], pw1[(2 * jp + 1) * 64 + c]}));
    }
    // W2 paired over out-channel o: W2p[j][op] = (w2[2op][j], w2[2op+1][j])
    for (int i = t; i < 1024; i += stride) {
        int j = i >> 5, op = i & 31;
        W2p[i] = u32of(__float22half2_rn({pw2[(2 * op) * 32 + j], pw2[(2 * op + 1) * 32 + j]}));
    }
    // offset-conv weights as duplicated half2: layout [c][k][18]
    for (int i = t; i < 3456; i += stride) {
        int ck = i / 18, d = i - ck * 18;
        float v = (d < 9) ? owc[d * 192 + ck] : owr[(d - 9) * 192 + ck];
        Wo2[i] = u32of(__float2half2_rn(v));
    }
    // MFMA A-fragment pack (f16): k' = tap*64 + c; per mode:
    // Wp[((s*4+wv)*64 + lane)*8 + e] = w[o=wv*16+(lane&15)][k'=32s+(lane>>4)*8+e]
    for (int i = t; i < 24576; i += stride) {
        int m = i >= 12288;
        int rem = i - m * 12288;
        int e = rem & 7, l = (rem >> 3) & 63, wv = (rem >> 9) & 3, s = rem >> 11;
        int kk = 32 * s + (l >> 4) * 8 + e;
        int o = wv * 16 + (l & 15);
        int c = kk & 63, tap = kk >> 6;
        const float* src = m ? wr : wc;
        Wp[i] = __float2half(src[o * 192 + c * 3 + tap]);
    }
}

// ---------------- preprocess: 1x1 conv 64->32->64, 1 pixel/thread ----------------
// Channel-paired half2 accumulators: hreg[16] (mid pairs) + acc[32] (out pairs).
// a_low -> NHWC f16 (ws) + NCHW f16 (d_out scratch). a_high -> NCHW f16 (ws).
__global__ __launch_bounds__(256) void k_pre(const float* __restrict__ alow,
                                             const float* __restrict__ ahigh,
                                             const float* __restrict__ b1,
                                             const float* __restrict__ b2,
                                             char* __restrict__ ws8,
                                             __half* __restrict__ anchw)
{
    const unsigned* __restrict__ W1p = (const unsigned*)(ws8 + OFF_W1);
    const unsigned* __restrict__ W2p = (const unsigned*)(ws8 + OFF_W2);
    int t = blockIdx.x * 256 + threadIdx.x;      // [0, 2*B*H*W)
    int tensor = t >> 18;
    int pix = t & 262143;
    int b = pix >> 16;
    int hw = pix & 65535;
    const float* __restrict__ x = (tensor ? ahigh : alow) + (size_t)b * Cn * HWn + hw;

    __half2 hreg[16];
#pragma unroll
    for (int jp = 0; jp < 16; jp++)
        hreg[jp] = __float22half2_rn({b1[2 * jp], b1[2 * jp + 1]});
#pragma unroll 8
    for (int c = 0; c < 64; c++) {
        __half2 xh = __float2half2_rn(x[(size_t)c * HWn]);
        const unsigned* wrow = W1p + c * 16;
#pragma unroll
        for (int jp = 0; jp < 16; jp++) hreg[jp] = __hfma2(bc2(wrow[jp]), xh, hreg[jp]);
    }
    __half2 acc[32];
#pragma unroll
    for (int op = 0; op < 32; op++)
        acc[op] = __float22half2_rn({b2[2 * op], b2[2 * op + 1]});
#pragma unroll
    for (int j = 0; j < 32; j++) {
        __half m = (j & 1) ? __high2half(hreg[j >> 1]) : __low2half(hreg[j >> 1]);
        __half2 md = __half2half2(m);
        const unsigned* wrow = W2p + j * 32;
#pragma unroll
        for (int op = 0; op < 32; op++) acc[op] = __hfma2(bc2(wrow[op]), md, acc[op]);
    }
    if (tensor == 0) {
        // NHWC (gather + epilogue a_low reads)
        __half* __restrict__ outp = (__half*)(ws8 + OFF_PRE_LOW) + (size_t)pix * 64;
#pragma unroll
        for (int q = 0; q < 8; q++) {
            uint4 u = { u32of(acc[q * 4 + 0]), u32of(acc[q * 4 + 1]),
                        u32of(acc[q * 4 + 2]), u32of(acc[q * 4 + 3]) };
            *reinterpret_cast<uint4*>(outp + q * 8) = u;
        }
        // NCHW copy (k_om2 reads); u16 stores fully coalesced
        __half* __restrict__ np = anchw + (size_t)b * Cn * HWn + hw;
#pragma unroll
        for (int op = 0; op < 32; op++) {
            np[(size_t)(2 * op) * HWn]     = __low2half(acc[op]);
            np[(size_t)(2 * op + 1) * HWn] = __high2half(acc[op]);
        }
    } else {
        // a_high: NCHW only (epilogue reads)
        __half* __restrict__ np = (__half*)(ws8 + OFF_PRE_HIGH) + (size_t)b * Cn * HWn + hw;
#pragma unroll
        for (int op = 0; op < 32; op++) {
            np[(size_t)(2 * op) * HWn]     = __low2half(acc[op]);
            np[(size_t)(2 * op + 1) * HWn] = __high2half(acc[op]);
        }
    }
}

// ---------------- offset convs: packed-f16, vectorized loads ----------------
__global__ __launch_bounds__(256) void k_om2(const __half* __restrict__ Anc,
                                             const float* __restrict__ ocb,
                                             const float* __restrict__ orb,
                                             char* __restrict__ ws8)
{
    const unsigned* __restrict__ Wo2 = (const unsigned*)(ws8 + OFF_WOF16);
    float* __restrict__ omc = (float*)(ws8 + OFF_OM_COL);
    float* __restrict__ omr = (float*)(ws8 + OFF_OM_ROW);
    int t = blockIdx.x * 256 + threadIdx.x;     // [0, B*H*W/4)
    int q = t & 63;
    int h = (t >> 6) & 255;
    int b = t >> 14;
    int w0 = q * 4;
    const __half* __restrict__ base = Anc + ((size_t)b * Cn) * HWn + (size_t)h * Wn + w0;

    const bool topOK = (h > 0), botOK = (h < Hn - 1);
    const bool lOK = (w0 > 0), rOK = (w0 + 4 < Wn);
    const int offT = topOK ? -Wn : 0;
    const int offB = botOK ? Wn : 0;
    const int offL = lOK ? -1 : 0;
    const int offR = rOK ? 4 : 3;

    const __half2 z = __float2half2_rn(0.f);
    const __half hz = __float2half(0.f);
    __half2 aC[9][2], aR[9][2];
#pragma unroll
    for (int d = 0; d < 9; d++) { aC[d][0] = z; aC[d][1] = z; aR[d][0] = z; aR[d][1] = z; }

    for (int c = 0; c < 64; c++) {
        const __half* pc = base + (size_t)c * HWn;
        uint2 qm = *reinterpret_cast<const uint2*>(pc + offT);
        uint2 q0 = *reinterpret_cast<const uint2*>(pc);
        uint2 qp = *reinterpret_cast<const uint2*>(pc + offB);
        __half L = lOK ? pc[offL] : hz;
        __half R = rOK ? pc[offR] : hz;
        __half2 m0 = topOK ? bc2(qm.x) : z, m1 = topOK ? bc2(qm.y) : z;
        __half2 c0 = bc2(q0.x), c1 = bc2(q0.y);
        __half2 p0 = botOK ? bc2(qp.x) : z, p1 = botOK ? bc2(qp.y) : z;
        __half2 X = __halves2half2(L, __low2half(c0));
        __half2 Y = __halves2half2(__high2half(c0), __low2half(c1));
        __half2 Z = __halves2half2(__high2half(c1), R);
        const unsigned* wb = Wo2 + c * 54;     // [k][18]
#pragma unroll
        for (int d = 0; d < 9; d++) {
            __half2 u0 = bc2(wb[d]), u1 = bc2(wb[18 + d]), u2 = bc2(wb[36 + d]);
            aC[d][0] = __hfma2(u0, m0, __hfma2(u1, c0, __hfma2(u2, p0, aC[d][0])));
            aC[d][1] = __hfma2(u0, m1, __hfma2(u1, c1, __hfma2(u2, p1, aC[d][1])));
            __half2 v0 = bc2(wb[9 + d]), v1 = bc2(wb[27 + d]), v2 = bc2(wb[45 + d]);
            aR[d][0] = __hfma2(v0, X, __hfma2(v1, c0, __hfma2(v2, Y, aR[d][0])));
            aR[d][1] = __hfma2(v0, Y, __hfma2(v1, c1, __hfma2(v2, Z, aR[d][1])));
        }
    }

    size_t ob = ((size_t)b * 9) * HWn + (size_t)h * Wn + w0;
#pragma unroll
    for (int d = 0; d < 9; d++) {
        float bcd = ocb[d], brd = orb[d];
        float4 vc = { __low2float(aC[d][0]) + bcd, __high2float(aC[d][0]) + bcd,
                      __low2float(aC[d][1]) + bcd, __high2float(aC[d][1]) + bcd };
        float4 vr = { __low2float(aR[d][0]) + brd, __high2float(aR[d][0]) + brd,
                      __low2float(aR[d][1]) + brd, __high2float(aR[d][1]) + brd };
        *reinterpret_cast<float4*>(omc + ob + (size_t)d * HWn) = vc;
        *reinterpret_cast<float4*>(omr + ob + (size_t)d * HWn) = vr;
    }
}

// ---------------- fused deformable conv (both dirs) + MFMA + epilogue ----------------
// 512 threads, 64 pixels/block. Gather: threads 0..383 own (mode,tap,pixel) with
// double-buffered corner loads. VB XOR-swizzled (slot^g&7). One barrier.
// 8 waves: waves 0-3 mode0 GEMM, 4-7 mode1. sigma via LDS (stride 66).
__global__ __launch_bounds__(512, 2) void k_dfuse(const float* __restrict__ bc,
                                                  const float* __restrict__ br,
                                                  float* __restrict__ out,
                                                  char* __restrict__ ws8)
{
    __shared__ __align__(16) unsigned smem[12288];   // 48 KB: VB u32[2][24][256]; EX f32[2][64][66] overlay

    const __half* __restrict__ A16 = (const __half*)(ws8 + OFF_PRE_LOW);

    int blk = blockIdx.x;                 // ((b*H + h)*4 + wt)
    int wt = blk & 3, bh = blk >> 2, h = bh & 255, b = bh >> 8;
    int w0 = wt * 64;
    int tid = threadIdx.x;

    // ---- decode + gather (threads 0..383; waves 0-2 mode0, 3-5 mode1) ----
    if (tid < 384) {
        int m = tid >= 192 ? 1 : 0;
        int r = tid - m * 192;
        int tap = r >> 6, p = r & 63;
        int w = w0 + p;
        const float* __restrict__ om = (const float*)(ws8 + (m ? OFF_OM_ROW : OFF_OM_COL));
        size_t ob = ((size_t)b * 9 * Hn + h) * Wn + w;
        float dy = om[ob + (size_t)tap * HWn];
        float dx = om[ob + (size_t)(3 + tap) * HWn];
        float mm = om[ob + (size_t)(6 + tap) * HWn];
        float mask = sigm(mm);
        float py = dy + (float)h + (m ? 0.f : (float)(tap - 1));
        float px = dx + (float)w + (m ? (float)(tap - 1) : 0.f);
        float fy = floorf(py), fx = floorf(px);
        float ty = py - fy, tx = px - fx;
        int y0 = (int)fy, x0 = (int)fx;
        int y1 = y0 + 1, x1 = x0 + 1;
        float vy0 = ((unsigned)y0 < (unsigned)Hn) ? 1.f : 0.f;
        float vy1 = ((unsigned)y1 < (unsigned)Hn) ? 1.f : 0.f;
        float vx0 = ((unsigned)x0 < (unsigned)Wn) ? 1.f : 0.f;
        float vx1 = ((unsigned)x1 < (unsigned)Wn) ? 1.f : 0.f;
        int y0c = min(max(y0, 0), Hn - 1), y1c = min(max(y1, 0), Hn - 1);
        int x0c = min(max(x0, 0), Wn - 1), x1c = min(max(x1, 0), Wn - 1);
        float ry = 1.f - ty, rx = 1.f - tx;
        int pbase = b * HWn;
        __half2 wh[4];
        wh[0] = __float2half2_rn(ry * rx * mask * vy0 * vx0);
        wh[1] = __float2half2_rn(ry * tx * mask * vy0 * vx1);
        wh[2] = __float2half2_rn(ty * rx * mask * vy1 * vx0);
        wh[3] = __float2half2_rn(ty * tx * mask * vy1 * vx1);
        int cb[4];
        cb[0] = (pbase + y0c * Wn + x0c) * 8;     // uint4-index: pix*128B/16
        cb[1] = (pbase + y0c * Wn + x1c) * 8;
        cb[2] = (pbase + y1c * Wn + x0c) * 8;
        cb[3] = (pbase + y1c * Wn + x1c) * 8;
        const uint4* __restrict__ Au = (const uint4*)A16;
        const __half2 z = __float2half2_rn(0.f);

        uint4 ra[4], rb[4], na[4], nb[4];
#pragma unroll
        for (int i = 0; i < 4; i++) { ra[i] = Au[cb[i]]; rb[i] = Au[cb[i] + 1]; }
#pragma unroll
        for (int c4 = 0; c4 < 4; c4++) {
            if (c4 < 3) {
#pragma unroll
                for (int i = 0; i < 4; i++) {
                    na[i] = Au[cb[i] + (c4 + 1) * 2];
                    nb[i] = Au[cb[i] + (c4 + 1) * 2 + 1];
                }
            }
            __half2 hs[8];
#pragma unroll
            for (int j = 0; j < 8; j++) hs[j] = z;
#pragma unroll
            for (int i = 0; i < 4; i++) {
                hs[0] = __hfma2(bc2(ra[i].x), wh[i], hs[0]);
                hs[1] = __hfma2(bc2(ra[i].y), wh[i], hs[1]);
                hs[2] = __hfma2(bc2(ra[i].z), wh[i], hs[2]);
                hs[3] = __hfma2(bc2(ra[i].w), wh[i], hs[3]);
                hs[4] = __hfma2(bc2(rb[i].x), wh[i], hs[4]);
                hs[5] = __hfma2(bc2(rb[i].y), wh[i], hs[5]);
                hs[6] = __hfma2(bc2(rb[i].z), wh[i], hs[6]);
                hs[7] = __hfma2(bc2(rb[i].w), wh[i], hs[7]);
            }
            int g0 = tap * 8 + c4 * 2;
            uint4 lo = { u32of(hs[0]), u32of(hs[1]), u32of(hs[2]), u32of(hs[3]) };
            uint4 hi = { u32of(hs[4]), u32of(hs[5]), u32of(hs[6]), u32of(hs[7]) };
            int sl0 = p ^ (g0 & 7);
            int sl1 = p ^ ((g0 + 1) & 7);
            *reinterpret_cast<uint4*>(&smem[m * 6144 + (g0 + 0) * 256 + sl0 * 4]) = lo;
            *reinterpret_cast<uint4*>(&smem[m * 6144 + (g0 + 1) * 256 + sl1 * 4]) = hi;
            if (c4 < 3) {
#pragma unroll
                for (int i = 0; i < 4; i++) { ra[i] = na[i]; rb[i] = nb[i]; }
            }
        }
    }
    __syncthreads();

    // ---- GEMM: wave wv: mode = wv>>2, o-slice = (wv&3)*16 ----
    int wv = tid >> 6;
    int lane = tid & 63;
    int m = wv >> 2;
    int wq = wv & 3;
    int kb = lane >> 4, n = lane & 15;
    const f16x8* __restrict__ Wp = reinterpret_cast<const f16x8*>(ws8 + OFF_WPACK + (size_t)m * 24576);
    f32x4 zero = {0.f, 0.f, 0.f, 0.f};
    f32x4 acc[4] = {zero, zero, zero, zero};
#pragma unroll
    for (int s = 0; s < 6; s++) {
        f16x8 af = Wp[(s * 4 + wq) * 64 + lane];
        int rr = s * 4 + kb;
#pragma unroll
        for (int pt = 0; pt < 4; pt++) {
            int sl = (pt * 16 + n) ^ (rr & 7);
            f16x8 bf = *reinterpret_cast<const f16x8*>(&smem[m * 6144 + rr * 256 + sl * 4]);
            acc[pt] = __builtin_amdgcn_mfma_f32_16x16x32_f16(af, bf, acc[pt], 0, 0, 0);
        }
    }
    // sigma in regs
    const float* __restrict__ bias = m ? br : bc;
    float bv[4];
#pragma unroll
    for (int rg = 0; rg < 4; rg++) bv[rg] = bias[wq * 16 + kb * 4 + rg];
    float sg[4][4];
#pragma unroll
    for (int pt = 0; pt < 4; pt++)
#pragma unroll
        for (int rg = 0; rg < 4; rg++) sg[pt][rg] = sigm(acc[pt][rg] + bv[rg]);
    __syncthreads();
    // EX overlay: [m][o][66] f32
    float* EX = reinterpret_cast<float*>(smem);
#pragma unroll
    for (int pt = 0; pt < 4; pt++)
#pragma unroll
        for (int rg = 0; rg < 4; rg++)
            EX[m * 4224 + (wq * 16 + kb * 4 + rg) * 66 + (pt * 16 + n)] = sg[pt][rg];
    __syncthreads();

    // ---- epilogue: thread t: pixel p = t&63, o-group = t>>6 (8 o's) ----
    int p = tid & 63, og = tid >> 6;
    int o0 = og * 8;
    size_t pix = ((size_t)b * Hn + h) * Wn + (w0 + p);
    uint4 ua = *reinterpret_cast<const uint4*>(A16 + pix * 64 + o0);
    const __half* ap = reinterpret_cast<const __half*>(&ua);
    const __half* __restrict__ Ahn = (const __half*)(ws8 + OFF_PRE_HIGH);
    size_t chbase = ((size_t)b * 64 + o0) * HWn + (size_t)h * Wn + (w0 + p);
#pragma unroll
    for (int j = 0; j < 8; j++) {
        float sc = EX[(o0 + j) * 66 + p];
        float sr = EX[4224 + (o0 + j) * 66 + p];
        float av = __half2float(ap[j]);
        float hv = __half2float(Ahn[chbase + (size_t)j * HWn]);
        out[chbase + (size_t)j * HWn] = 2.f * av + (sc + sr) * hv;
    }
}

extern "C" void kernel_launch(void* const* d_in, const int* in_sizes, int n_in,
                              void* d_out, int out_size, void* d_ws, size_t ws_size,
                              hipStream_t stream)
{
    const float* a_low  = (const float*)d_in[0];
    const float* a_high = (const float*)d_in[1];
    const float* pre_w1 = (const float*)d_in[2];
    const float* pre_b1 = (const float*)d_in[3];
    const float* pre_w2 = (const float*)d_in[4];
    const float* pre_b2 = (const float*)d_in[5];
    const float* offc_w = (const float*)d_in[6];
    const float* offc_b = (const float*)d_in[7];
    const float* wc     = (const float*)d_in[8];
    const float* bc     = (const float*)d_in[9];
    const float* offr_w = (const float*)d_in[10];
    const float* offr_b = (const float*)d_in[11];
    const float* wr     = (const float*)d_in[12];
    const float* br     = (const float*)d_in[13];
    float* out = (float*)d_out;
    char* ws8  = (char*)d_ws;

    hipLaunchKernelGGL(k_repack, dim3(128), dim3(256), 0, stream,
                       pre_w1, pre_w2, offc_w, offr_w, wc, wr, ws8);
    // k_pre writes NCHW f16 copy of preprocessed a_low into d_out
    // (scratch; fully overwritten by k_dfuse epilogue, which never reads d_out)
    hipLaunchKernelGGL(k_pre, dim3(2048), dim3(256), 0, stream,
                       a_low, a_high, pre_b1, pre_b2, ws8, (__half*)d_out);
    hipLaunchKernelGGL(k_om2, dim3(256), dim3(256), 0, stream,
                       (const __half*)d_out, offc_b, offr_b, ws8);
    hipLaunchKernelGGL(k_dfuse, dim3(4096), dim3(512), 0, stream,
                       bc, br, out, ws8);
}